// Round 7
// baseline (10860.685 us; speedup 1.0000x reference)
//
#include <hip/hip_runtime.h>
#include <cstdint>
#include <cstddef>

#define NODES   55
#define BGRAPH  16384
#define NTOT    (BGRAPH*NODES)    // 901120
#define INCH    13
#define HID     32
#define ETOT    (4*NTOT)          // 3604480
#define NCHUNK  (NTOT/1024)       // 880 exact
#define NPB     128
#define LCAP    1024

typedef _Float16 f16;
typedef _Float16 f16x4 __attribute__((ext_vector_type(4))); // 8B
typedef _Float16 f16x8 __attribute__((ext_vector_type(8))); // 16B

__device__ __forceinline__ float selu_f(float v){
  const float s  = 1.0507009873554805f;
  const float sa = 1.7580993408473766f;
  return v > 0.f ? s*v : sa*(__expf(v)-1.f);
}

// ---------------- build kernels (shared) ----------------
__global__ void k_hist2(const int* __restrict__ a, const int* __restrict__ b,
                        int* __restrict__ da, int* __restrict__ db){
  int e = blockIdx.x*256 + threadIdx.x;
  if (e < ETOT){ atomicAdd(&da[a[e]], 1); atomicAdd(&db[b[e]], 1); }
}

__global__ void k_hist(const int* __restrict__ dst, int* __restrict__ deg){
  int e = blockIdx.x*256 + threadIdx.x;
  if (e < ETOT) atomicAdd(&deg[dst[e]], 1);
}

__global__ void k_scan1(const int* __restrict__ deg, int* __restrict__ part){
  __shared__ int sd[256];
  int b = blockIdx.x, t = threadIdx.x;
  const int4* p = (const int4*)(deg + b*1024);
  int4 v = p[t];
  sd[t] = v.x+v.y+v.z+v.w;
  __syncthreads();
  for (int o=128;o>0;o>>=1){ if (t<o) sd[t]+=sd[t+o]; __syncthreads(); }
  if (t==0) part[b] = sd[0];
}

__global__ void k_scan2(int* __restrict__ part, int nc){
  __shared__ int sd[1024];
  int t = threadIdx.x;
  int orig = (t<nc) ? part[t] : 0;
  sd[t] = orig;
  __syncthreads();
  for (int o=1;o<1024;o<<=1){
    int v = (t>=o) ? sd[t-o] : 0;
    __syncthreads();
    sd[t] += v;
    __syncthreads();
  }
  if (t<nc) part[t] = sd[t] - orig;   // exclusive
}

__global__ void k_scan3(const int* __restrict__ deg, const int* __restrict__ part,
                        int* __restrict__ off){
  __shared__ int sd[256];
  int b = blockIdx.x, t = threadIdx.x;
  const int4* p = (const int4*)(deg + b*1024);
  int4 v = p[t];
  int s = v.x+v.y+v.z+v.w;
  sd[t] = s;
  __syncthreads();
  for (int o=1;o<256;o<<=1){
    int val = (t>=o) ? sd[t-o] : 0;
    __syncthreads();
    sd[t] += val;
    __syncthreads();
  }
  int base = part[b] + sd[t] - s;
  int i = b*1024 + t*4;
  off[i]   = base;
  off[i+1] = base + v.x;
  off[i+2] = base + v.x + v.y;
  off[i+3] = base + v.x + v.y + v.z;
  if (b==0 && t==0) off[NTOT] = ETOT;
}

// CSC fill: edges sorted by src, payload = dst id
__global__ void k_fillS(const int* __restrict__ src, const int* __restrict__ dst,
                        int* __restrict__ cur, int* __restrict__ dstS){
  int e = blockIdx.x*256 + threadIdx.x;
  if (e >= ETOT) return;
  int s = src[e];
  int pos = atomicAdd(&cur[s], 1);
  dstS[pos] = dst[e];
}

// CSR fill (fallback path): packed src | dst_local<<20
__global__ void k_fill(const int* __restrict__ src, const int* __restrict__ dst,
                       int* __restrict__ cur, uint32_t* __restrict__ csrp){
  int e = blockIdx.x*256 + threadIdx.x;
  if (e >= ETOT) return;
  int d = dst[e];
  int pos = atomicAdd(&cur[d], 1);
  csrp[pos] = (uint32_t)src[e] | (((uint32_t)d & 127u) << 20);
}

// ================= SCATTER PATH =================
// layer0 scatter: x (fp32,13ch) -> aggG[dst]
__global__ __launch_bounds__(256,8) void k_xscat(
    const float* __restrict__ x,
    const int* __restrict__ offS, const int* __restrict__ dstS,
    float* __restrict__ aggG, int dlo, int dhi)
{
  int t = threadIdx.x;
  int node = blockIdx.x*16 + (t>>4);
  int c = t & 15;
  float xv = (c < INCH) ? x[(size_t)node*INCH + c] : 0.f;
  int s0 = offS[node], s1 = offS[node+1];
  for (int j=s0; j<s1; j++){
    int d = dstS[j];
    if (c < INCH && d >= dlo && d < dhi)
      atomicAdd(aggG + (size_t)(d-dlo)*INCH + c, xv);
  }
}

// layers 1-4 scatter: h (f16,32ch) -> aggG[dst] (fp32)
__global__ __launch_bounds__(256,8) void k_scat(
    const f16* __restrict__ h,
    const int* __restrict__ offS, const int* __restrict__ dstS,
    float* __restrict__ aggG, int dlo, int dhi)
{
  int t = threadIdx.x;
  int node = blockIdx.x*32 + (t>>3);
  int l = t & 7;
  f16x4 hv = *(const f16x4*)(h + (size_t)node*HID + 4*l);
  float f0=(float)hv[0], f1=(float)hv[1], f2=(float)hv[2], f3=(float)hv[3];
  int s0 = offS[node], s1 = offS[node+1];
  for (int j=s0; j<s1; j++){
    int d = dstS[j];
    if (d >= dlo && d < dhi){
      float* b = aggG + (size_t)(d-dlo)*HID + 4*l;
      atomicAdd(b+0, f0); atomicAdd(b+1, f1);
      atomicAdd(b+2, f2); atomicAdd(b+3, f3);
    }
  }
}

// layer0 transform: agg@wl0+bl0 + x@wr0, selu -> h, jk
__global__ __launch_bounds__(256,8) void k_trans0(
    const float* __restrict__ x, const float* __restrict__ aggG,
    const int* __restrict__ degD,
    const float* __restrict__ wl0, const float* __restrict__ bl0,
    const float* __restrict__ wr0,
    f16* __restrict__ h, f16* __restrict__ jk, int dlo)
{
  __shared__ f16 ST[128*34];
  int t = threadIdx.x;
  int nl = t & 127;
  int node = dlo + blockIdx.x*128 + nl;
  int oc0 = __builtin_amdgcn_readfirstlane((t>>7)*16);
  int cnt = degD[node]; if (cnt<1) cnt=1;
  float inv = 1.f/(float)cnt;
  const float* xr = x + (size_t)node*INCH;
  const float* ar = aggG + (size_t)(node-dlo)*INCH;
  float acc[16];
  #pragma unroll
  for (int j=0;j<16;j++) acc[j] = bl0[oc0+j];
  #pragma unroll
  for (int cc=0;cc<INCH;cc++){
    float xc = xr[cc];
    float mc = ar[cc]*inv;
    #pragma unroll
    for (int j=0;j<16;j++)
      acc[j] = fmaf(xc, wr0[cc*HID+oc0+j], fmaf(mc, wl0[cc*HID+oc0+j], acc[j]));
  }
  #pragma unroll
  for (int j=0;j<16;j++) ST[nl*34 + oc0 + j] = (f16)selu_f(acc[j]);
  __syncthreads();
  const uint32_t* STd = (const uint32_t*)ST;
  uint4* ho4 = (uint4*)h;
  uint4* jo4 = (uint4*)jk;
  size_t gbase = (size_t)(dlo + blockIdx.x*128) * 4;   // 16B chunks
  #pragma unroll
  for (int k=0;k<2;k++){
    int cch = t + 256*k;
    int n = cch>>2, m = cch&3;
    int d = n*17 + m*4;
    uint4 u;
    u.x=STd[d]; u.y=STd[d+1]; u.z=STd[d+2]; u.w=STd[d+3];
    ho4[gbase+cch] = u;
    jo4[gbase+cch] = u;
  }
}

// layers 1-4 transform: agg@wl+bl + h@wr, selu -> h (in place), jk=max
__global__ __launch_bounds__(256,8) void k_trans(
    const float* __restrict__ aggG, const int* __restrict__ degD,
    const float* __restrict__ wl, const float* __restrict__ bl,
    const float* __restrict__ wr,
    f16* __restrict__ h, f16* __restrict__ jk, int dlo)
{
  __shared__ f16 ST[128*34];
  int t = threadIdx.x;
  int nl = t & 127;
  int node = dlo + blockIdx.x*128 + nl;
  int oc0 = __builtin_amdgcn_readfirstlane((t>>7)*16);
  int cnt = degD[node]; if (cnt<1) cnt=1;
  float inv = 1.f/(float)cnt;
  const f16x8* h8 = (const f16x8*)(h + (size_t)node*HID);
  const float4* a4 = (const float4*)(aggG + (size_t)(node-dlo)*HID);
  float acc[16];
  #pragma unroll
  for (int j=0;j<16;j++) acc[j] = bl[oc0+j];
  #pragma unroll
  for (int jj=0;jj<4;jj++){
    f16x8 vh = h8[jj];
    float4 a0 = a4[2*jj], a1 = a4[2*jj+1];
    float m[8] = {a0.x,a0.y,a0.z,a0.w,a1.x,a1.y,a1.z,a1.w};
    #pragma unroll
    for (int r=0;r<8;r++){
      int cc = 8*jj+r;
      float hc = (float)vh[r];
      float mc = m[r]*inv;
      #pragma unroll
      for (int j=0;j<16;j++)
        acc[j] = fmaf(hc, wr[cc*HID+oc0+j], fmaf(mc, wl[cc*HID+oc0+j], acc[j]));
    }
  }
  #pragma unroll
  for (int j=0;j<16;j++) ST[nl*34 + oc0 + j] = (f16)selu_f(acc[j]);
  __syncthreads();
  const uint32_t* STd = (const uint32_t*)ST;
  uint4* ho4 = (uint4*)h;
  uint4* jo4 = (uint4*)jk;
  size_t gbase = (size_t)(dlo + blockIdx.x*128) * 4;
  #pragma unroll
  for (int k=0;k<2;k++){
    int cch = t + 256*k;
    int n = cch>>2, m = cch&3;
    int d = n*17 + m*4;
    union { uint4 u; f16 hh[8]; } hv, jv;
    hv.u.x=STd[d]; hv.u.y=STd[d+1]; hv.u.z=STd[d+2]; hv.u.w=STd[d+3];
    jv.u = jo4[gbase+cch];
    #pragma unroll
    for (int r=0;r<8;r++){
      float a = (float)jv.hh[r], b = (float)hv.hh[r];
      jv.hh[r] = (f16)fmaxf(a, b);
    }
    ho4[gbase+cch] = hv.u;
    jo4[gbase+cch] = jv.u;
  }
}

// ================= FALLBACK PATH (R5 gather kernels) =================
__global__ __launch_bounds__(256,8) void k_layer0(
    const float* __restrict__ x,
    const int* __restrict__ off, const uint32_t* __restrict__ csrp,
    const float* __restrict__ wl0, const float* __restrict__ bl0,
    const float* __restrict__ wr0,
    f16* __restrict__ hout, f16* __restrict__ jkout)
{
  __shared__ float AG0[NPB*INCH];
  __shared__ f16   ST0[NPB*34];
  int t = threadIdx.x;
  int base = blockIdx.x*NPB;
  for (int i=t; i<NPB*INCH; i+=256) AG0[i] = 0.f;
  __syncthreads();
  int e0 = off[base], e1 = off[base+NPB];
  int slot = t >> 4, c = t & 15;
  if (c < INCH){
    for (int eb=e0; eb<e1; eb+=64){
      int a0 = eb+slot, a1 = a0+16, a2 = a0+32, a3 = a0+48;
      bool q0=a0<e1, q1=a1<e1, q2=a2<e1, q3=a3<e1;
      int m0=q0?a0:e1-1, m1=q1?a1:e1-1, m2=q2?a2:e1-1, m3=q3?a3:e1-1;
      uint32_t k0=csrp[m0], k1=csrp[m1], k2=csrp[m2], k3=csrp[m3];
      float v0 = x[(size_t)((k0&0xFFFFFu)*INCH + c)];
      float v1 = x[(size_t)((k1&0xFFFFFu)*INCH + c)];
      float v2 = x[(size_t)((k2&0xFFFFFu)*INCH + c)];
      float v3 = x[(size_t)((k3&0xFFFFFu)*INCH + c)];
      atomicAdd(AG0 + ((k0>>20)&127u)*INCH + c, q0?v0:0.f);
      atomicAdd(AG0 + ((k1>>20)&127u)*INCH + c, q1?v1:0.f);
      atomicAdd(AG0 + ((k2>>20)&127u)*INCH + c, q2?v2:0.f);
      atomicAdd(AG0 + ((k3>>20)&127u)*INCH + c, q3?v3:0.f);
    }
  }
  __syncthreads();
  int nl = t & 127;
  int node = base + (t < 128 ? nl : nl + 128);
  // (two half-blocks of 128 nodes each, thread=node over 256)
  node = base + t;
  int cnt = off[node+1]-off[node]; if (cnt<1) cnt=1;
  float inv = 1.f/(float)cnt;
  const float* xr = x + (size_t)node*INCH;
  float acc2[HID];
  #pragma unroll
  for (int oc=0;oc<HID;oc++) acc2[oc] = bl0[oc];
  #pragma unroll
  for (int cc=0;cc<INCH;cc++){
    float xc = xr[cc];
    float mc = AG0[(t&127)*INCH+cc]*((t<128)?inv:0.f); // unreachable for t>=128 in NPB=128 grid
    mc = AG0[(t&127)*INCH+cc]*inv;
    #pragma unroll
    for (int oc=0;oc<HID;oc++)
      acc2[oc] = fmaf(xc, wr0[cc*HID+oc], fmaf(mc, wl0[cc*HID+oc], acc2[oc]));
  }
  if (t < NPB){
    f16x8* ho = (f16x8*)(hout + (size_t)node*HID);
    f16x8* jo = (f16x8*)(jkout + (size_t)node*HID);
    #pragma unroll
    for (int j=0;j<4;j++){
      f16x8 v;
      #pragma unroll
      for (int r=0;r<8;r++) v[r] = (f16)selu_f(acc2[8*j+r]);
      ho[j] = v; jo[j] = v;
    }
  }
}

__global__ __launch_bounds__(256,8) void k_layer(
    const f16* __restrict__ hin,
    const int* __restrict__ off, const uint32_t* __restrict__ csrp,
    const float* __restrict__ wl, const float* __restrict__ bl,
    const float* __restrict__ wr,
    f16* __restrict__ hout, f16* __restrict__ jkio)
{
  __shared__ float AGf[NPB*33];
  int t = threadIdx.x;
  int base = blockIdx.x*NPB;
  for (int i=t; i<NPB*33; i+=256) AGf[i] = 0.f;
  __syncthreads();
  int e0 = off[base], e1 = off[base+NPB];
  int slot = t >> 3, l = t & 7;
  for (int eb=e0; eb<e1; eb+=128){
    int a0 = eb+slot, a1 = a0+32, a2 = a0+64, a3 = a0+96;
    bool q0=a0<e1, q1=a1<e1, q2=a2<e1, q3=a3<e1;
    int m0=q0?a0:e1-1, m1=q1?a1:e1-1, m2=q2?a2:e1-1, m3=q3?a3:e1-1;
    uint32_t k0=csrp[m0], k1=csrp[m1], k2=csrp[m2], k3=csrp[m3];
    f16x4 g0 = *(const f16x4*)(hin + (size_t)((k0&0xFFFFFu)*32u + 4u*l));
    f16x4 g1 = *(const f16x4*)(hin + (size_t)((k1&0xFFFFFu)*32u + 4u*l));
    f16x4 g2 = *(const f16x4*)(hin + (size_t)((k2&0xFFFFFu)*32u + 4u*l));
    f16x4 g3 = *(const f16x4*)(hin + (size_t)((k3&0xFFFFFu)*32u + 4u*l));
    float* d0 = AGf + ((k0>>20)&127u)*33 + 4*l;
    float* d1 = AGf + ((k1>>20)&127u)*33 + 4*l;
    float* d2 = AGf + ((k2>>20)&127u)*33 + 4*l;
    float* d3 = AGf + ((k3>>20)&127u)*33 + 4*l;
    #pragma unroll
    for (int j=0;j<4;j++) atomicAdd(d0+j, q0?(float)g0[j]:0.f);
    #pragma unroll
    for (int j=0;j<4;j++) atomicAdd(d1+j, q1?(float)g1[j]:0.f);
    #pragma unroll
    for (int j=0;j<4;j++) atomicAdd(d2+j, q2?(float)g2[j]:0.f);
    #pragma unroll
    for (int j=0;j<4;j++) atomicAdd(d3+j, q3?(float)g3[j]:0.f);
  }
  __syncthreads();
  int nl = t & 127;
  int node = base + nl;
  int oc0 = __builtin_amdgcn_readfirstlane((t>>7)*16);
  int cnt = off[node+1]-off[node]; if (cnt < 1) cnt = 1;
  float inv = 1.f/(float)cnt;
  const f16x8* h8 = (const f16x8*)(hin + (size_t)node*HID);
  float acc[16];
  #pragma unroll
  for (int j=0;j<16;j++) acc[j] = bl[oc0+j];
  #pragma unroll
  for (int jj=0;jj<4;jj++){
    f16x8 vh = h8[jj];
    #pragma unroll
    for (int r=0;r<8;r++){
      int cc = 8*jj+r;
      float hc = (float)vh[r];
      float mc = AGf[nl*33+cc]*inv;
      #pragma unroll
      for (int j=0;j<16;j++)
        acc[j] = fmaf(hc, wr[cc*HID+oc0+j], fmaf(mc, wl[cc*HID+oc0+j], acc[j]));
    }
  }
  __syncthreads();
  f16* ST = (f16*)AGf;
  #pragma unroll
  for (int j=0;j<16;j++) ST[nl*34 + oc0 + j] = (f16)selu_f(acc[j]);
  __syncthreads();
  const uint32_t* STd = (const uint32_t*)AGf;
  uint4* ho4 = (uint4*)hout;
  uint4* jo4 = (uint4*)jkio;
  int gbase = blockIdx.x*(NPB*HID/8);
  #pragma unroll
  for (int k=0;k<2;k++){
    int cch = t + 256*k;
    int n = cch>>2, m = cch&3;
    int d = n*17 + m*4;
    union { uint4 u; f16 hh[8]; } hv, jv;
    hv.u.x=STd[d]; hv.u.y=STd[d+1]; hv.u.z=STd[d+2]; hv.u.w=STd[d+3];
    jv.u = jo4[gbase+cch];
    #pragma unroll
    for (int r=0;r<8;r++){
      float a = (float)jv.hh[r], b = (float)hv.hh[r];
      jv.hh[r] = (f16)fmaxf(a, b);
    }
    ho4[gbase+cch] = hv.u;
    jo4[gbase+cch] = jv.u;
  }
}

// ---------------- attention + head ----------------
__global__ __launch_bounds__(256) void k_attn(
    const f16* __restrict__ jk, const float* __restrict__ x,
    const int* __restrict__ shuf,
    const float* __restrict__ wq, const float* __restrict__ bq,
    const float* __restrict__ wk, const float* __restrict__ bk,
    const float* __restrict__ wv, const float* __restrict__ bv,
    const float* __restrict__ wo, const float* __restrict__ bo,
    const float* __restrict__ wfc, const float* __restrict__ bfc,
    float* __restrict__ out)
{
  __shared__ float H[NODES*33];
  __shared__ float K[NODES*33];
  __shared__ float V[NODES*33];
  __shared__ float Wq[HID*HID];
  __shared__ float Wo[HID*HID];
  __shared__ float Wfc[192*6];
  __shared__ float Qs[6*33];
  __shared__ float S[6*56];
  __shared__ float O[6*33];
  __shared__ float SO[192];
  __shared__ float part[96];
  __shared__ float M[NODES];
  __shared__ int order[8];
  __shared__ int sel[6];

  int g = blockIdx.x, t = threadIdx.x;
  for (int i=t; i<HID*HID; i+=256){ Wq[i]=wq[i]; Wo[i]=wo[i]; }
  for (int i=t; i<192*6;   i+=256){ Wfc[i]=wfc[i]; }
  {
    const f16x8* j8 = (const f16x8*)(jk + (size_t)g*NODES*HID);
    for (int i=t; i<NODES*HID/8; i+=256){
      f16x8 v = j8[i];
      int node = i >> 2, c0 = (i & 3)*8;
      #pragma unroll
      for (int r=0;r<8;r++) H[node*33 + c0 + r] = selu_f((float)v[r]);
    }
  }
  if (t < NODES) M[t] = x[(size_t)(g*NODES+t)*INCH + (INCH-3)];
  __syncthreads();
  if (t == 0){
    int c = 0;
    for (int n=0;n<NODES;n++) if (M[n] > 0.5f && c < 6) order[c++] = n;
  }
  __syncthreads();
  if (t < 6) sel[t] = order[shuf[g*6 + t]];
  __syncthreads();

  {
    int k = t & 63;
    int ocg = __builtin_amdgcn_readfirstlane(t >> 6);
    const float* wkp = wk + ocg*8;
    const float* wvp = wv + ocg*8;
    if (k < NODES){
      float ak[8], av[8];
      #pragma unroll
      for (int j=0;j<8;j++){ ak[j]=bk[ocg*8+j]; av[j]=bv[ocg*8+j]; }
      #pragma unroll
      for (int c=0;c<HID;c++){
        float hv = H[k*33+c];
        #pragma unroll
        for (int j=0;j<8;j++){
          ak[j] = fmaf(hv, wkp[c*HID+j], ak[j]);
          av[j] = fmaf(hv, wvp[c*HID+j], av[j]);
        }
      }
      #pragma unroll
      for (int j=0;j<8;j++){ K[k*33+ocg*8+j]=ak[j]; V[k*33+ocg*8+j]=av[j]; }
    }
  }
  if (t < 192){
    int q = t>>5, oc = t&31;
    int node = sel[q];
    float a = bq[oc];
    #pragma unroll
    for (int c=0;c<HID;c++) a = fmaf(H[node*33+c], Wq[c*HID+oc], a);
    Qs[q*33+oc] = a;
  }
  __syncthreads();

  for (int idx=t; idx<6*NODES; idx+=256){
    int q = idx % 6, k = idx / 6;
    float a = 0.f;
    #pragma unroll
    for (int c=0;c<HID;c++) a = fmaf(Qs[q*33+c], K[k*33+c], a);
    S[q*56+k] = a * 0.17677669529663687f;
  }
  __syncthreads();

  if (t < 192){
    int q = t>>5, l = t&31;
    float v0 = (l      < NODES) ? S[q*56+l]    : -1e30f;
    float v1 = (l+32   < NODES) ? S[q*56+l+32] : -1e30f;
    float mx = fmaxf(v0, v1);
    #pragma unroll
    for (int o=16;o>0;o>>=1) mx = fmaxf(mx, __shfl_xor(mx, o, 32));
    float p0 = (l    < NODES) ? __expf(v0-mx) : 0.f;
    float p1 = (l+32 < NODES) ? __expf(v1-mx) : 0.f;
    float sm = p0 + p1;
    #pragma unroll
    for (int o=16;o>0;o>>=1) sm += __shfl_xor(sm, o, 32);
    float inv = 1.f/sm;
    if (l    < NODES) S[q*56+l]    = p0*inv;
    if (l+32 < NODES) S[q*56+l+32] = p1*inv;
  }
  __syncthreads();

  if (t < 192){
    int q = t>>5, oc = t&31;
    float a = 0.f;
    for (int k=0;k<NODES;k++) a = fmaf(S[q*56+k], V[k*33+oc], a);
    O[q*33+oc] = a;
  }
  __syncthreads();

  if (t < 192){
    int q = t>>5, oc = t&31;
    float a = bo[oc];
    #pragma unroll
    for (int c=0;c<HID;c++) a = fmaf(O[q*33+c], Wo[c*HID+oc], a);
    SO[t] = selu_f(a);
  }
  __syncthreads();

  if (t < 96){
    int j = t % 6, pp = t / 6;
    float a = 0.f;
    #pragma unroll
    for (int r=0;r<12;r++) a = fmaf(SO[pp*12+r], Wfc[(pp*12+r)*6+j], a);
    part[pp*6+j] = a;
  }
  __syncthreads();
  if (t < 6){
    float a = bfc[t];
    #pragma unroll
    for (int pp=0;pp<16;pp++) a += part[pp*6+t];
    out[g*6+t] = a;
  }
}

extern "C" void kernel_launch(void* const* d_in, const int* in_sizes, int n_in,
                              void* d_out, int out_size, void* d_ws, size_t ws_size,
                              hipStream_t stream)
{
  const float* x   = (const float*)d_in[0];
  const int*   eix = (const int*)d_in[1];
  const int*   shf = (const int*)d_in[2];
  const float* wl0 = (const float*)d_in[3];
  const float* bl0 = (const float*)d_in[4];
  const float* wr0 = (const float*)d_in[5];
  const float* wl  = (const float*)d_in[6];
  const float* bl  = (const float*)d_in[7];
  const float* wr  = (const float*)d_in[8];
  const float* wq  = (const float*)d_in[9];
  const float* bq  = (const float*)d_in[10];
  const float* wk  = (const float*)d_in[11];
  const float* bk  = (const float*)d_in[12];
  const float* wv  = (const float*)d_in[13];
  const float* bv  = (const float*)d_in[14];
  const float* wo  = (const float*)d_in[15];
  const float* bo  = (const float*)d_in[16];
  const float* wfc = (const float*)d_in[17];
  const float* bfc = (const float*)d_in[18];
  float* out = (float*)d_out;

  const int* esrc = eix;
  const int* edst = eix + ETOT;

  char* p0 = (char*)d_ws;
  size_t used = 0;
  auto carve = [&](size_t bytes)->void*{
    void* r = (void*)(p0 + used);
    used += (bytes + 255) & ~(size_t)255;
    return r;
  };

  // scatter path needs: degD + offS + dstS + aggG(fp32 full) + h + jk = 252.3 MB
  size_t need_scatter =
      ((sizeof(int)*NTOT + 255) & ~(size_t)255) +
      ((sizeof(int)*(NTOT+1) + 255) & ~(size_t)255) +
      ((sizeof(int)*(size_t)ETOT + 255) & ~(size_t)255) +
      ((sizeof(float)*(size_t)NTOT*HID + 255) & ~(size_t)255) +
      2*((2*(size_t)NTOT*HID + 255) & ~(size_t)255);

  if (ws_size >= need_scatter){
    // ---------- scatter path ----------
    int*   degD = (int*)carve(sizeof(int)*NTOT);
    int*   offS = (int*)carve(sizeof(int)*(NTOT+1));
    int*   dstS = (int*)carve(sizeof(int)*(size_t)ETOT);
    float* aggG = (float*)carve(sizeof(float)*(size_t)NTOT*HID);
    f16*   h16  = (f16*)carve(2*(size_t)NTOT*HID);
    f16*   jk16 = (f16*)carve(2*(size_t)NTOT*HID);
    // build-time scratch inside aggG region (free until layer0 scatter)
    int* srcdeg = (int*)aggG;
    int* curS   = srcdeg + NTOT;
    int* partB  = curS + NTOT;

    hipMemsetAsync(degD, 0, sizeof(int)*NTOT, stream);
    hipMemsetAsync(srcdeg, 0, sizeof(int)*NTOT, stream);
    k_hist2<<<ETOT/256, 256, 0, stream>>>(esrc, edst, srcdeg, degD);
    k_scan1<<<NCHUNK, 256, 0, stream>>>(srcdeg, partB);
    k_scan2<<<1, 1024, 0, stream>>>(partB, NCHUNK);
    k_scan3<<<NCHUNK, 256, 0, stream>>>(srcdeg, partB, offS);
    hipMemcpyAsync(curS, offS, sizeof(int)*NTOT, hipMemcpyDeviceToDevice, stream);
    k_fillS<<<ETOT/256, 256, 0, stream>>>(esrc, edst, curS, dstS);

    // layer 0
    hipMemsetAsync(aggG, 0, sizeof(float)*(size_t)NTOT*INCH, stream);
    k_xscat<<<NTOT/16, 256, 0, stream>>>(x, offS, dstS, aggG, 0, NTOT);
    k_trans0<<<NTOT/128, 256, 0, stream>>>(x, aggG, degD, wl0, bl0, wr0, h16, jk16, 0);
    // layers 1..4
    for (int l=0; l<4; l++){
      hipMemsetAsync(aggG, 0, sizeof(float)*(size_t)NTOT*HID, stream);
      k_scat<<<NTOT/32, 256, 0, stream>>>(h16, offS, dstS, aggG, 0, NTOT);
      k_trans<<<NTOT/128, 256, 0, stream>>>(aggG, degD,
                                            wl + l*HID*HID, bl + l*HID, wr + l*HID*HID,
                                            h16, jk16, 0);
    }
    k_attn<<<BGRAPH, 256, 0, stream>>>(jk16, x, shf,
                                       wq, bq, wk, bk, wv, bv, wo, bo, wfc, bfc, out);
  } else {
    // ---------- fallback: R5 gather path (195 MB) ----------
    int*      deg  = (int*)carve(sizeof(int)*NTOT);
    int*      off  = (int*)carve(sizeof(int)*(NTOT+1));
    int*      partB= (int*)carve(sizeof(int)*1024);
    uint32_t* csrp = (uint32_t*)carve(sizeof(uint32_t)*(size_t)ETOT);
    f16*      h_a  = (f16*)carve(2*(size_t)NTOT*HID);
    f16*      h_b  = (f16*)carve(2*(size_t)NTOT*HID);
    f16*      jk16 = (f16*)carve(2*(size_t)NTOT*HID);

    hipMemsetAsync(deg, 0, sizeof(int)*NTOT, stream);
    k_hist <<<ETOT/256, 256, 0, stream>>>(edst, deg);
    k_scan1<<<NCHUNK, 256, 0, stream>>>(deg, partB);
    k_scan2<<<1, 1024, 0, stream>>>(partB, NCHUNK);
    k_scan3<<<NCHUNK, 256, 0, stream>>>(deg, partB, off);
    hipMemcpyAsync(deg, off, sizeof(int)*NTOT, hipMemcpyDeviceToDevice, stream);
    k_fill <<<ETOT/256, 256, 0, stream>>>(esrc, edst, deg, csrp);

    k_layer0<<<NTOT/NPB, 256, 0, stream>>>(x, off, csrp, wl0, bl0, wr0, h_a, jk16);
    f16* hc = h_a; f16* hn = h_b;
    for (int l=0; l<4; l++){
      k_layer<<<NTOT/NPB, 256, 0, stream>>>(hc, off, csrp,
                                            wl + l*HID*HID, bl + l*HID, wr + l*HID*HID,
                                            hn, jk16);
      f16* tmp = hc; hc = hn; hn = tmp;
    }
    k_attn<<<BGRAPH, 256, 0, stream>>>(jk16, x, shf,
                                       wq, bq, wk, bk, wv, bv, wo, bo, wfc, bfc, out);
  }
}

// Round 8
// 4130.764 us; speedup vs baseline: 2.6292x; 2.6292x over previous
//
#include <hip/hip_runtime.h>
#include <cstdint>
#include <cstddef>

#define NODES   55
#define BGRAPH  16384
#define NTOT    (BGRAPH*NODES)    // 901120
#define INCH    13
#define HID     32
#define ETOT    (4*NTOT)          // 3604480
#define NCHUNK  (NTOT/1024)       // 880 exact
#define NPART   5
#define NQ      (NTOT/NPART)      // 180224 (=128*1408)
#define EVCAPE  (ETOT/NPART + 8192)   // quarter edges + 10.8 sigma margin

typedef _Float16 f16;
typedef _Float16 f16x4 __attribute__((ext_vector_type(4))); // 8B
typedef _Float16 f16x8 __attribute__((ext_vector_type(8))); // 16B

__device__ __forceinline__ float selu_f(float v){
  const float s  = 1.0507009873554805f;
  const float sa = 1.7580993408473766f;
  return v > 0.f ? s*v : sa*(__expf(v)-1.f);
}

// ---------------- CSR/CSC build ----------------
__global__ void k_hist2(const int* __restrict__ a, const int* __restrict__ b,
                        int* __restrict__ da, int* __restrict__ db){
  int e = blockIdx.x*256 + threadIdx.x;
  if (e < ETOT){ atomicAdd(&da[a[e]], 1); atomicAdd(&db[b[e]], 1); }
}

__global__ void k_scan1(const int* __restrict__ deg, int* __restrict__ part){
  __shared__ int sd[256];
  int b = blockIdx.x, t = threadIdx.x;
  const int4* p = (const int4*)(deg + b*1024);
  int4 v = p[t];
  sd[t] = v.x+v.y+v.z+v.w;
  __syncthreads();
  for (int o=128;o>0;o>>=1){ if (t<o) sd[t]+=sd[t+o]; __syncthreads(); }
  if (t==0) part[b] = sd[0];
}

__global__ void k_scan2(int* __restrict__ part, int nc){
  __shared__ int sd[1024];
  int t = threadIdx.x;
  int orig = (t<nc) ? part[t] : 0;
  sd[t] = orig;
  __syncthreads();
  for (int o=1;o<1024;o<<=1){
    int v = (t>=o) ? sd[t-o] : 0;
    __syncthreads();
    sd[t] += v;
    __syncthreads();
  }
  if (t<nc) part[t] = sd[t] - orig;   // exclusive
}

__global__ void k_scan3(const int* __restrict__ deg, const int* __restrict__ part,
                        int* __restrict__ off){
  __shared__ int sd[256];
  int b = blockIdx.x, t = threadIdx.x;
  const int4* p = (const int4*)(deg + b*1024);
  int4 v = p[t];
  int s = v.x+v.y+v.z+v.w;
  sd[t] = s;
  __syncthreads();
  for (int o=1;o<256;o<<=1){
    int val = (t>=o) ? sd[t-o] : 0;
    __syncthreads();
    sd[t] += val;
    __syncthreads();
  }
  int base = part[b] + sd[t] - s;
  int i = b*1024 + t*4;
  off[i]   = base;
  off[i+1] = base + v.x;
  off[i+2] = base + v.x + v.y;
  off[i+3] = base + v.x + v.y + v.z;
  if (b==0 && t==0) off[NTOT] = ETOT;
}

// mapS[csc_pos] = csr_pos
__global__ void k_fill2(const int* __restrict__ src, const int* __restrict__ dst,
                        int* __restrict__ curS, int* __restrict__ curD,
                        uint32_t* __restrict__ mapS){
  int e = blockIdx.x*256 + threadIdx.x;
  if (e >= ETOT) return;
  int s = src[e], d = dst[e];
  int ps = atomicAdd(&curS[s], 1);
  int pd = atomicAdd(&curD[d], 1);
  mapS[ps] = (uint32_t)pd;
}

// ---------------- pass A: scatter h rows to EV (CSR order), full-line stores ----
__global__ __launch_bounds__(256,8) void k_sc(
    const f16* __restrict__ hin,
    const int* __restrict__ offS, const int* __restrict__ off,
    const uint32_t* __restrict__ mapS,
    f16* __restrict__ EV, int nodeLo, int nodeHi)
{
  int t = threadIdx.x;
  int node = blockIdx.x*32 + (t>>3);
  int l = t & 7;
  uint32_t ebase = (uint32_t)off[nodeLo];
  uint32_t span  = (uint32_t)off[nodeHi] - ebase;
  if (span > (uint32_t)EVCAPE) span = EVCAPE;
  f16x4 hv = *(const f16x4*)(hin + (size_t)node*HID + 4*l);
  int s0 = offS[node], s1 = offS[node+1];
  for (int j=s0; j<s1; j++){
    uint32_t rel = mapS[j] - ebase;
    if (rel < span)
      *(f16x4*)(EV + (size_t)rel*HID + 4*l) = hv;
  }
}

// layer0 variant: x rows (13 fp32) into EV0 rows of 16 fp32 (64B lines)
__global__ __launch_bounds__(256,8) void k_sc0(
    const float* __restrict__ x,
    const int* __restrict__ offS, const int* __restrict__ off,
    const uint32_t* __restrict__ mapS,
    float* __restrict__ EV0, int nodeLo, int nodeHi)
{
  int t = threadIdx.x;
  int node = blockIdx.x*16 + (t>>4);
  int c = t & 15;
  uint32_t ebase = (uint32_t)off[nodeLo];
  uint32_t span  = (uint32_t)off[nodeHi] - ebase;
  if (span > (uint32_t)EVCAPE) span = EVCAPE;
  float xv = (c < INCH) ? x[(size_t)node*INCH + c] : 0.f;
  int s0 = offS[node], s1 = offS[node+1];
  for (int j=s0; j<s1; j++){
    uint32_t rel = mapS[j] - ebase;
    if (rel < span)
      EV0[(size_t)rel*16 + c] = xv;
  }
}

// ---------------- pass B: sequential reduce over EV + transform ----------------
__global__ __launch_bounds__(256,8) void k_red(
    const f16* __restrict__ hin, const f16* __restrict__ EV,
    const int* __restrict__ off,
    const float* __restrict__ wl, const float* __restrict__ bl,
    const float* __restrict__ wr,
    f16* __restrict__ hout, f16* __restrict__ jkio, int nodeLo)
{
  __shared__ f16 AG[128*34];   // means; reused as output staging
  int t = threadIdx.x;
  int base = nodeLo + blockIdx.x*128;
  int ebase = off[nodeLo];
  int l = t & 7, sub = t >> 3;           // 8 lanes (4ch) per node, 32 nodes/pass
  for (int p=0; p<4; p++){
    int nl = p*32 + sub;
    int node = base + nl;
    int s0 = off[node], s1 = off[node+1];
    float a0=0.f,a1=0.f,a2=0.f,a3=0.f;
    for (int j=s0; j<s1; j++){
      f16x4 v = *(const f16x4*)(EV + (size_t)(j-ebase)*HID + 4*l);
      a0 += (float)v[0]; a1 += (float)v[1];
      a2 += (float)v[2]; a3 += (float)v[3];
    }
    int cnt = s1-s0; if (cnt<1) cnt=1;
    float inv = 1.f/(float)cnt;
    f16* row = AG + nl*34 + 4*l;
    row[0]=(f16)(a0*inv); row[1]=(f16)(a1*inv);
    row[2]=(f16)(a2*inv); row[3]=(f16)(a3*inv);
  }
  __syncthreads();
  // phase 2: node = base+(t&127), oc half = t>>7 (wave-uniform -> scalar weights)
  int nl = t & 127;
  int node = base + nl;
  int oc0 = __builtin_amdgcn_readfirstlane((t>>7)*16);
  const f16x8* h8 = (const f16x8*)(hin + (size_t)node*HID);
  float acc[16];
  #pragma unroll
  for (int j=0;j<16;j++) acc[j] = bl[oc0+j];
  #pragma unroll
  for (int jj=0;jj<4;jj++){
    f16x8 vh = h8[jj];
    #pragma unroll
    for (int r=0;r<8;r++){
      int cc = 8*jj+r;
      float hc = (float)vh[r];
      float mc = (float)AG[nl*34+cc];
      #pragma unroll
      for (int j=0;j<16;j++)
        acc[j] = fmaf(hc, wr[cc*HID+oc0+j], fmaf(mc, wl[cc*HID+oc0+j], acc[j]));
    }
  }
  __syncthreads();   // all AG reads done
  #pragma unroll
  for (int j=0;j<16;j++) AG[nl*34 + oc0 + j] = (f16)selu_f(acc[j]);
  __syncthreads();
  const uint32_t* STd = (const uint32_t*)AG;
  uint4* ho4 = (uint4*)hout;
  uint4* jo4 = (uint4*)jkio;
  size_t gbase = (size_t)base * 4;      // 16B chunks (4 per 64B row)
  #pragma unroll
  for (int k=0;k<2;k++){
    int cch = t + 256*k;
    int n = cch>>2, m = cch&3;
    int d = n*17 + m*4;
    union { uint4 u; f16 hh[8]; } hv, jv;
    hv.u.x=STd[d]; hv.u.y=STd[d+1]; hv.u.z=STd[d+2]; hv.u.w=STd[d+3];
    jv.u = jo4[gbase+cch];
    #pragma unroll
    for (int r=0;r<8;r++){
      float a = (float)jv.hh[r], b = (float)hv.hh[r];
      jv.hh[r] = (f16)fmaxf(a, b);
    }
    ho4[gbase+cch] = hv.u;
    jo4[gbase+cch] = jv.u;
  }
}

__global__ __launch_bounds__(256,8) void k_red0(
    const float* __restrict__ x, const float* __restrict__ EV0,
    const int* __restrict__ off,
    const float* __restrict__ wl0, const float* __restrict__ bl0,
    const float* __restrict__ wr0,
    f16* __restrict__ hout, f16* __restrict__ jkout, int nodeLo)
{
  __shared__ float AG0[128*13];   // stride 13 (odd -> conflict-free)
  __shared__ f16   ST0[128*34];
  int t = threadIdx.x;
  int base = nodeLo + blockIdx.x*128;
  int ebase = off[nodeLo];
  int c = t & 15, sub = t >> 4;          // 16 lanes/node, 16 nodes/pass
  for (int p=0; p<8; p++){
    int nl = p*16 + sub;
    int node = base + nl;
    int s0 = off[node], s1 = off[node+1];
    if (c < INCH){
      float s = 0.f;
      for (int j=s0; j<s1; j++)
        s += EV0[(size_t)(j-ebase)*16 + c];
      int cnt = s1-s0; if (cnt<1) cnt=1;
      AG0[nl*INCH + c] = s/(float)cnt;
    }
  }
  __syncthreads();
  int nl = t & 127;
  int node = base + nl;
  int oc0 = __builtin_amdgcn_readfirstlane((t>>7)*16);
  const float* xr = x + (size_t)node*INCH;
  float acc[16];
  #pragma unroll
  for (int j=0;j<16;j++) acc[j] = bl0[oc0+j];
  #pragma unroll
  for (int cc=0;cc<INCH;cc++){
    float xc = xr[cc];
    float mc = AG0[nl*INCH+cc];
    #pragma unroll
    for (int j=0;j<16;j++)
      acc[j] = fmaf(xc, wr0[cc*HID+oc0+j], fmaf(mc, wl0[cc*HID+oc0+j], acc[j]));
  }
  #pragma unroll
  for (int j=0;j<16;j++) ST0[nl*34 + oc0 + j] = (f16)selu_f(acc[j]);
  __syncthreads();
  const uint32_t* STd = (const uint32_t*)ST0;
  uint4* ho4 = (uint4*)hout;
  uint4* jo4 = (uint4*)jkout;
  size_t gbase = (size_t)base * 4;
  #pragma unroll
  for (int k=0;k<2;k++){
    int cch = t + 256*k;
    int n = cch>>2, m = cch&3;
    int d = n*17 + m*4;
    uint4 u;
    u.x=STd[d]; u.y=STd[d+1]; u.z=STd[d+2]; u.w=STd[d+3];
    ho4[gbase+cch] = u;
    jo4[gbase+cch] = u;
  }
}

// ---------------- attention + head, one block per graph ----------------
__global__ __launch_bounds__(256) void k_attn(
    const f16* __restrict__ jk, const float* __restrict__ x,
    const int* __restrict__ shuf,
    const float* __restrict__ wq, const float* __restrict__ bq,
    const float* __restrict__ wk, const float* __restrict__ bk,
    const float* __restrict__ wv, const float* __restrict__ bv,
    const float* __restrict__ wo, const float* __restrict__ bo,
    const float* __restrict__ wfc, const float* __restrict__ bfc,
    float* __restrict__ out)
{
  __shared__ float H[NODES*33];
  __shared__ float K[NODES*33];
  __shared__ float V[NODES*33];
  __shared__ float Wq[HID*HID];
  __shared__ float Wo[HID*HID];
  __shared__ float Wfc[192*6];
  __shared__ float Qs[6*33];
  __shared__ float S[6*56];
  __shared__ float O[6*33];
  __shared__ float SO[192];
  __shared__ float part[96];
  __shared__ float M[NODES];
  __shared__ int order[8];
  __shared__ int sel[6];

  int g = blockIdx.x, t = threadIdx.x;
  for (int i=t; i<HID*HID; i+=256){ Wq[i]=wq[i]; Wo[i]=wo[i]; }
  for (int i=t; i<192*6;   i+=256){ Wfc[i]=wfc[i]; }
  {
    const f16x8* j8 = (const f16x8*)(jk + (size_t)g*NODES*HID);
    for (int i=t; i<NODES*HID/8; i+=256){
      f16x8 v = j8[i];
      int node = i >> 2, c0 = (i & 3)*8;
      #pragma unroll
      for (int r=0;r<8;r++) H[node*33 + c0 + r] = selu_f((float)v[r]);
    }
  }
  if (t < NODES) M[t] = x[(size_t)(g*NODES+t)*INCH + (INCH-3)];
  __syncthreads();
  if (t == 0){
    int c = 0;
    for (int n=0;n<NODES;n++) if (M[n] > 0.5f && c < 6) order[c++] = n;
  }
  __syncthreads();
  if (t < 6) sel[t] = order[shuf[g*6 + t]];
  __syncthreads();

  {
    int k = t & 63;
    int ocg = __builtin_amdgcn_readfirstlane(t >> 6);
    const float* wkp = wk + ocg*8;
    const float* wvp = wv + ocg*8;
    if (k < NODES){
      float ak[8], av[8];
      #pragma unroll
      for (int j=0;j<8;j++){ ak[j]=bk[ocg*8+j]; av[j]=bv[ocg*8+j]; }
      #pragma unroll
      for (int c=0;c<HID;c++){
        float hv = H[k*33+c];
        #pragma unroll
        for (int j=0;j<8;j++){
          ak[j] = fmaf(hv, wkp[c*HID+j], ak[j]);
          av[j] = fmaf(hv, wvp[c*HID+j], av[j]);
        }
      }
      #pragma unroll
      for (int j=0;j<8;j++){ K[k*33+ocg*8+j]=ak[j]; V[k*33+ocg*8+j]=av[j]; }
    }
  }
  if (t < 192){
    int q = t>>5, oc = t&31;
    int node = sel[q];
    float a = bq[oc];
    #pragma unroll
    for (int c=0;c<HID;c++) a = fmaf(H[node*33+c], Wq[c*HID+oc], a);
    Qs[q*33+oc] = a;
  }
  __syncthreads();

  for (int idx=t; idx<6*NODES; idx+=256){
    int q = idx % 6, k = idx / 6;
    float a = 0.f;
    #pragma unroll
    for (int c=0;c<HID;c++) a = fmaf(Qs[q*33+c], K[k*33+c], a);
    S[q*56+k] = a * 0.17677669529663687f;
  }
  __syncthreads();

  if (t < 192){
    int q = t>>5, l = t&31;
    float v0 = (l      < NODES) ? S[q*56+l]    : -1e30f;
    float v1 = (l+32   < NODES) ? S[q*56+l+32] : -1e30f;
    float mx = fmaxf(v0, v1);
    #pragma unroll
    for (int o=16;o>0;o>>=1) mx = fmaxf(mx, __shfl_xor(mx, o, 32));
    float p0 = (l    < NODES) ? __expf(v0-mx) : 0.f;
    float p1 = (l+32 < NODES) ? __expf(v1-mx) : 0.f;
    float sm = p0 + p1;
    #pragma unroll
    for (int o=16;o>0;o>>=1) sm += __shfl_xor(sm, o, 32);
    float inv = 1.f/sm;
    if (l    < NODES) S[q*56+l]    = p0*inv;
    if (l+32 < NODES) S[q*56+l+32] = p1*inv;
  }
  __syncthreads();

  if (t < 192){
    int q = t>>5, oc = t&31;
    float a = 0.f;
    for (int k=0;k<NODES;k++) a = fmaf(S[q*56+k], V[k*33+oc], a);
    O[q*33+oc] = a;
  }
  __syncthreads();

  if (t < 192){
    int q = t>>5, oc = t&31;
    float a = bo[oc];
    #pragma unroll
    for (int c=0;c<HID;c++) a = fmaf(O[q*33+c], Wo[c*HID+oc], a);
    SO[t] = selu_f(a);
  }
  __syncthreads();

  if (t < 96){
    int j = t % 6, pp = t / 6;
    float a = 0.f;
    #pragma unroll
    for (int r=0;r<12;r++) a = fmaf(SO[pp*12+r], Wfc[(pp*12+r)*6+j], a);
    part[pp*6+j] = a;
  }
  __syncthreads();
  if (t < 6){
    float a = bfc[t];
    #pragma unroll
    for (int pp=0;pp<16;pp++) a += part[pp*6+t];
    out[g*6+t] = a;
  }
}

extern "C" void kernel_launch(void* const* d_in, const int* in_sizes, int n_in,
                              void* d_out, int out_size, void* d_ws, size_t ws_size,
                              hipStream_t stream)
{
  const float* x   = (const float*)d_in[0];
  const int*   eix = (const int*)d_in[1];
  const int*   shf = (const int*)d_in[2];
  const float* wl0 = (const float*)d_in[3];
  const float* bl0 = (const float*)d_in[4];
  const float* wr0 = (const float*)d_in[5];
  const float* wl  = (const float*)d_in[6];
  const float* bl  = (const float*)d_in[7];
  const float* wr  = (const float*)d_in[8];
  const float* wq  = (const float*)d_in[9];
  const float* bq  = (const float*)d_in[10];
  const float* wk  = (const float*)d_in[11];
  const float* bk  = (const float*)d_in[12];
  const float* wv  = (const float*)d_in[13];
  const float* bv  = (const float*)d_in[14];
  const float* wo  = (const float*)d_in[15];
  const float* bo  = (const float*)d_in[16];
  const float* wfc = (const float*)d_in[17];
  const float* bfc = (const float*)d_in[18];
  float* out = (float*)d_out;

  const int* esrc = eix;
  const int* edst = eix + ETOT;

  // workspace carve — total ~241 MB (< 252.3 MB known-available from R7)
  char* p0 = (char*)d_ws;
  size_t used = 0;
  auto carve = [&](size_t bytes)->void*{
    void* r = (void*)(p0 + used);
    used += (bytes + 255) & ~(size_t)255;
    return r;
  };
  int*      off  = (int*)carve(sizeof(int)*(NTOT+1));     // CSR offsets (by dst)
  int*      offS = (int*)carve(sizeof(int)*(NTOT+1));     // CSC offsets (by src)
  uint32_t* mapS = (uint32_t*)carve(sizeof(uint32_t)*(size_t)ETOT);
  f16*      EV   = (f16*)carve((size_t)EVCAPE*HID*2);     // 46.7 MB edge-value buffer
  f16*      h_a  = (f16*)carve(2*(size_t)NTOT*HID);
  f16*      h_b  = (f16*)carve(2*(size_t)NTOT*HID);
  f16*      jk16 = (f16*)carve(2*(size_t)NTOT*HID);
  float*    EV0  = (float*)EV;                            // layer0 rows: 16 fp32 = 64B

  // build temps live inside EV (free until first k_sc0)
  int* sdeg = (int*)EV;            // NTOT
  int* ddeg = sdeg + NTOT;         // NTOT
  int* pA   = ddeg + NTOT;         // 1024

  hipMemsetAsync(sdeg, 0, sizeof(int)*2*NTOT, stream);
  k_hist2<<<ETOT/256, 256, 0, stream>>>(esrc, edst, sdeg, ddeg);
  k_scan1<<<NCHUNK, 256, 0, stream>>>(sdeg, pA);
  k_scan2<<<1, 1024, 0, stream>>>(pA, NCHUNK);
  k_scan3<<<NCHUNK, 256, 0, stream>>>(sdeg, pA, offS);
  k_scan1<<<NCHUNK, 256, 0, stream>>>(ddeg, pA);
  k_scan2<<<1, 1024, 0, stream>>>(pA, NCHUNK);
  k_scan3<<<NCHUNK, 256, 0, stream>>>(ddeg, pA, off);
  // reuse deg arrays as fill cursors
  hipMemcpyAsync(sdeg, offS, sizeof(int)*NTOT, hipMemcpyDeviceToDevice, stream);
  hipMemcpyAsync(ddeg, off,  sizeof(int)*NTOT, hipMemcpyDeviceToDevice, stream);
  k_fill2<<<ETOT/256, 256, 0, stream>>>(esrc, edst, sdeg, ddeg, mapS);

  // layer 0 (x -> h_a, jk)
  for (int q=0; q<NPART; q++){
    int lo = q*NQ, hi = lo+NQ;
    k_sc0 <<<NTOT/16, 256, 0, stream>>>(x, offS, off, mapS, EV0, lo, hi);
    k_red0<<<NQ/128,  256, 0, stream>>>(x, EV0, off, wl0, bl0, wr0, h_a, jk16, lo);
  }
  // layers 1..4
  f16* hc = h_a; f16* hn = h_b;
  for (int l=0; l<4; l++){
    for (int q=0; q<NPART; q++){
      int lo = q*NQ, hi = lo+NQ;
      k_sc <<<NTOT/32, 256, 0, stream>>>(hc, offS, off, mapS, EV, lo, hi);
      k_red<<<NQ/128,  256, 0, stream>>>(hc, EV, off,
                                         wl + l*HID*HID, bl + l*HID, wr + l*HID*HID,
                                         hn, jk16, lo);
    }
    f16* tmp = hc; hc = hn; hn = tmp;
  }
  k_attn<<<BGRAPH, 256, 0, stream>>>(jk16, x, shf,
                                     wq, bq, wk, bk, wv, bv, wo, bo, wfc, bfc, out);
}